// Round 15
// baseline (213.551 us; speedup 1.0000x reference)
//
#include <hip/hip_runtime.h>
#include <hip/hip_fp16.h>
#include <hip/hip_cooperative_groups.h>

namespace cgrp = cooperative_groups;

#define NT 256          // f(x) table size
#define NBATCH 1024
#define NOUT 65536      // 1024*64

#if __has_builtin(__builtin_amdgcn_exp2f)
#define EXP2(x) __builtin_amdgcn_exp2f(x)
#else
#define EXP2(x) exp2f(x)
#endif

// ---- graph constants (baked from the reference) ----
__constant__ int c_e1[17] = {0,0,1,2,2,3,4,5,6,8,8,9,10,11,11,13,14};
__constant__ int c_e2[17] = {1,4,2,3,5,4,12,6,7,9,12,10,11,12,13,14,15};
__constant__ int c_p0[24] = {1,0,1,1,3,2,0,0,3,2,5,5,9,8,9,10,10,12,4,4,8,11,13,13};
__constant__ int c_p1[24] = {4,2,3,5,5,4,3,12,12,6,7,6,12,10,11,11,13,13,8,11,11,14,15,14};
__constant__ int c_ni[24] = {0,1,2,2,2,3,4,4,4,5,6,7,8,9,10,11,11,11,12,12,12,13,14,15};

// 6 unordered products (a<=b). E_ab symmetric => ovl = W + W^T,
// W = sum pref_ab * C_a E_ab C_b^T  (diagonal gets pref/2, folded into exp arg).
__constant__ int c_pa[6]   = {0,0,0,1,1,2};
__constant__ int c_pb[6]   = {0,1,2,1,2,2};
__constant__ int c_diag[6] = {1,0,0,1,0,1};

static __device__ __forceinline__ float2 up2(unsigned u) {
  __half2 h = *reinterpret_cast<__half2*>(&u);
  return __half22float2(h);
}

// ---- kernel 0: one-block prep — transformed fp16 C' + sigma consts ----
// Batch-invariant work hoisted out of the 1024-block hot kernel (was ~150
// VALU + strided cg reads per thread per block).
__global__ void k_prep(const float* __restrict__ cgr,
                       const float* __restrict__ sigp,
                       __half* __restrict__ ctg, float* __restrict__ consts) {
  const int t = threadIdx.x;
  for (int idx = t; idx < 3 * 81 * 8; idx += 256) {
    int s = idx / 648;
    int rem = idx - s * 648;
    int j = rem >> 3, q = rem & 7;
    int col = s * 81 + j;
    int off = j - 33;
    float v;
    if (off >= 0 && (off & 1)) v = -cgr[q * 243 + (col - 1)];
    else                       v =  cgr[q * 243 + col];
    ctg[idx] = __float2half(v);
  }
  if (t == 0) {
    float sg[3];
    sg[0] = 0.4f * __expf(sigp[0]);
    sg[1] = 0.8f * __expf(sigp[1]);
    sg[2] = 1.2f * __expf(sigp[2]);
    #pragma unroll
    for (int p = 0; p < 6; ++p) {
      float sa = sg[c_pa[p]], sb = sg[c_pb[p]];
      float s2 = sa * sa + sb * sb;
      float rr = 2.0f * sa * sb / s2;
      consts[p]     = (-0.5f / s2) * 1.44269504088896f;    // cInv (log2e folded)
      consts[6 + p] = 1.5f * __log2f(rr) - (float)c_diag[p]; // cLgp (diag: /2)
    }
  }
}

// ---- fused cooperative kernel: ovl -> grid.sync -> table -> grid.sync -> interp
// Phase A is r14's proven k_ovl body (grid 1024, 256 thr, two-phase via LDS,
// named scalar accums, fp16 CT/V). Coop fusion removes 2 kernel-boundary
// drains + 2 launch overheads. 1024 blocks @ (256,6) => co-residency OK.
__global__ __launch_bounds__(256, 6)
void k_fused(const float* __restrict__ pos, const __half* __restrict__ ctg,
             const float* __restrict__ consts,
             const float* __restrict__ ew, const float* __restrict__ eb,
             const float* __restrict__ mup, const float* __restrict__ lrp,
             const float* __restrict__ W1, const float* __restrict__ b1,
             const float* __restrict__ W2, const float* __restrict__ b2,
             const float* __restrict__ W3, const float* __restrict__ b3,
             float* __restrict__ xbuf, float* __restrict__ bmin,
             float* __restrict__ bmax, float* __restrict__ mmf,
             float* __restrict__ table, float* __restrict__ out) {
  // smem floats: posS[48] | P4[81][4]=324 | CTh 1944 halves = 972 |
  // alias{ Vh 3888 halves = 1944 , red16[16][65] = 1040 } | cInv[6] cLgp[6]
  __shared__ __align__(16) float smem[3300];
  float* posS          = smem;                               // [48]
  float (*P4)[4]       = (float(*)[4])(smem + 48);           // [81][4]
  __half (*CTh)[81][8] = (__half(*)[81][8])(smem + 372);     // fp16 C'
  __half (*Vh)[81][8]  = (__half(*)[81][8])(smem + 1344);    // fp16 V
  float (*red16)[65]   = (float(*)[65])(smem + 1344);        // ALIAS of Vh
  float* cInv          = smem + 3288;                        // [6]
  float* cLgp          = smem + 3294;                        // [6]

  const int bid = blockIdx.x;
  const int t = threadIdx.x;

  // ======== PHASE A: per-batch ovl ========
  if (t < 48) posS[t] = pos[bid * 48 + t];
  if (t < 243) ((uint4*)CTh)[t] = ((const uint4*)ctg)[t];   // coalesced copy
  if (t >= 244 && t < 256) (smem + 3288)[t - 244] = consts[t - 244];
  __syncthreads();

  // 81 block points: 16 atoms, 17 bond midpoints, 24 pairs x 2 cross points
  if (t < 81) {
    float x, y, z;
    if (t < 16) {
      x = posS[t * 3]; y = posS[t * 3 + 1]; z = posS[t * 3 + 2];
    } else if (t < 33) {
      int e = t - 16;
      int a0 = c_e1[e] * 3, a1 = c_e2[e] * 3;
      x = 0.5f * (posS[a0] + posS[a1]);
      y = 0.5f * (posS[a0 + 1] + posS[a1 + 1]);
      z = 0.5f * (posS[a0 + 2] + posS[a1 + 2]);
    } else {
      int k = (t - 33) >> 1, sgn = (t - 33) & 1;
      float sc = sgn ? 0.25f : -0.25f;
      int n = c_ni[k] * 3, a0 = c_p0[k] * 3, a1 = c_p1[k] * 3;
      x = posS[n]     + sc * (posS[a0]     - posS[a1]);
      y = posS[n + 1] + sc * (posS[a0 + 1] - posS[a1 + 1]);
      z = posS[n + 2] + sc * (posS[a0 + 2] - posS[a1 + 2]);
    }
    P4[t][0] = x; P4[t][1] = y; P4[t][2] = z;
    P4[t][3] = x * x + y * y + z * z;
  }
  __syncthreads();

  // V phase: 246 tasks = (product s, 2-row strip); strip 40 = 1 row
  if (t < 246) {
    const int s = t / 41;
    const int st = t - s * 41;
    const int i0 = st * 2;
    const bool two = (st < 40);
    const int i1 = two ? i0 + 1 : i0;
    const int bb = c_pb[s];
    const float nInv = cInv[s];
    const float lgp  = cLgp[s];
    const float m2 = -2.0f * nInv;

    const float4 pA = *(const float4*)P4[i0];
    const float4 pB = *(const float4*)P4[i1];
    const float qAx = m2 * pA.x, qAy = m2 * pA.y, qAz = m2 * pA.z;
    const float qBx = m2 * pB.x, qBy = m2 * pB.y, qBz = m2 * pB.z;
    const float cA = fmaf(pA.w, nInv, lgp);
    const float cB = fmaf(pB.w, nInv, lgp);

    __half2 a0 = __float2half2_rn(0.0f), a1 = a0, a2 = a0, a3 = a0;
    __half2 b0 = a0, b1 = a0, b2 = a0, b3 = a0;

    for (int j = 0; j < 33; ++j) {
      const float4 pj = *(const float4*)P4[j];
      const float sj = pj.w * nInv;
      const float aA = fmaf(qAx, pj.x, fmaf(qAy, pj.y, fmaf(qAz, pj.z, sj + cA)));
      const float aB = fmaf(qBx, pj.x, fmaf(qBy, pj.y, fmaf(qBz, pj.z, sj + cB)));
      const __half2 hA = __float2half2_rn(EXP2(aA));
      const __half2 hB = __float2half2_rn(EXP2(aB));
      const uint4 cu = *(const uint4*)&CTh[bb][j][0];
      const __half2 c0 = *reinterpret_cast<const __half2*>(&cu.x);
      const __half2 c1 = *reinterpret_cast<const __half2*>(&cu.y);
      const __half2 c2 = *reinterpret_cast<const __half2*>(&cu.z);
      const __half2 c3 = *reinterpret_cast<const __half2*>(&cu.w);
      a0 = __hfma2(hA, c0, a0); a1 = __hfma2(hA, c1, a1);
      a2 = __hfma2(hA, c2, a2); a3 = __hfma2(hA, c3, a3);
      b0 = __hfma2(hB, c0, b0); b1 = __hfma2(hB, c1, b1);
      b2 = __hfma2(hB, c2, b2); b3 = __hfma2(hB, c3, b3);
    }

    for (int k = 0; k < 24; ++k) {
      const int jp = 33 + (k << 1);
      const float4 pp = *(const float4*)P4[jp];
      const float4 pm = *(const float4*)P4[jp + 1];
      const float sp = pp.w * nInv;
      const float sm = pm.w * nInv;
      const float aAp = fmaf(qAx, pp.x, fmaf(qAy, pp.y, fmaf(qAz, pp.z, sp + cA)));
      const float aBp = fmaf(qBx, pp.x, fmaf(qBy, pp.y, fmaf(qBz, pp.z, sp + cB)));
      const float aAm = fmaf(qAx, pm.x, fmaf(qAy, pm.y, fmaf(qAz, pm.z, sm + cA)));
      const float aBm = fmaf(qBx, pm.x, fmaf(qBy, pm.y, fmaf(qBz, pm.z, sm + cB)));
      const __half2 hA = __float2half2_rn(EXP2(aAp) - EXP2(aAm));
      const __half2 hB = __float2half2_rn(EXP2(aBp) - EXP2(aBm));
      const uint4 cu = *(const uint4*)&CTh[bb][jp][0];
      const __half2 c0 = *reinterpret_cast<const __half2*>(&cu.x);
      const __half2 c1 = *reinterpret_cast<const __half2*>(&cu.y);
      const __half2 c2 = *reinterpret_cast<const __half2*>(&cu.z);
      const __half2 c3 = *reinterpret_cast<const __half2*>(&cu.w);
      a0 = __hfma2(hA, c0, a0); a1 = __hfma2(hA, c1, a1);
      a2 = __hfma2(hA, c2, a2); a3 = __hfma2(hA, c3, a3);
      b0 = __hfma2(hB, c0, b0); b1 = __hfma2(hB, c1, b1);
      b2 = __hfma2(hB, c2, b2); b3 = __hfma2(hB, c3, b3);
    }

    __half2* voA = (__half2*)&Vh[s][i0][0];
    voA[0] = a0; voA[1] = a1; voA[2] = a2; voA[3] = a3;
    if (two) {
      __half2* voB = (__half2*)&Vh[s][i0 + 1][0];
      voB[0] = b0; voB[1] = b1; voB[2] = b2; voB[3] = b3;
    }
  }
  __syncthreads();

  // stage 2 (register-blocked 4x4, fp32 accum)
  float w00=0,w01=0,w02=0,w03=0, w10=0,w11=0,w12=0,w13=0;
  float w20=0,w21=0,w22=0,w23=0, w30=0,w31=0,w32=0,w33=0;
  const int ch = t & 15;
  if (t < 64) {
    const int pg = (t >> 5) & 1;
    const int qg = (t >> 4) & 1;
    const int ib = ch * 5;
    const int ie = (ch == 15) ? 81 : ib + 5;
    #pragma unroll
    for (int s = 0; s < 6; ++s) {
      const int lf = c_pa[s];
      for (int i = ib; i < ie; ++i) {
        const uint2 cu = *(const uint2*)&CTh[lf][i][pg * 4];
        const float2 p01 = up2(cu.x), p23 = up2(cu.y);
        const uint2 vu = *(const uint2*)&Vh[s][i][qg * 4];
        const float2 q01 = up2(vu.x), q23 = up2(vu.y);
        w00 = fmaf(p01.x, q01.x, w00); w01 = fmaf(p01.x, q01.y, w01);
        w02 = fmaf(p01.x, q23.x, w02); w03 = fmaf(p01.x, q23.y, w03);
        w10 = fmaf(p01.y, q01.x, w10); w11 = fmaf(p01.y, q01.y, w11);
        w12 = fmaf(p01.y, q23.x, w12); w13 = fmaf(p01.y, q23.y, w13);
        w20 = fmaf(p23.x, q01.x, w20); w21 = fmaf(p23.x, q01.y, w21);
        w22 = fmaf(p23.x, q23.x, w22); w23 = fmaf(p23.x, q23.y, w23);
        w30 = fmaf(p23.y, q01.x, w30); w31 = fmaf(p23.y, q01.y, w31);
        w32 = fmaf(p23.y, q23.x, w32); w33 = fmaf(p23.y, q23.y, w33);
      }
    }
  }
  __syncthreads();
  if (t < 64) {
    const int pg = (t >> 5) & 1;
    const int qg = (t >> 4) & 1;
    const int base = pg * 32 + qg * 4;
    red16[ch][base + 0 * 8 + 0] = w00; red16[ch][base + 0 * 8 + 1] = w01;
    red16[ch][base + 0 * 8 + 2] = w02; red16[ch][base + 0 * 8 + 3] = w03;
    red16[ch][base + 1 * 8 + 0] = w10; red16[ch][base + 1 * 8 + 1] = w11;
    red16[ch][base + 1 * 8 + 2] = w12; red16[ch][base + 1 * 8 + 3] = w13;
    red16[ch][base + 2 * 8 + 0] = w20; red16[ch][base + 2 * 8 + 1] = w21;
    red16[ch][base + 2 * 8 + 2] = w22; red16[ch][base + 2 * 8 + 3] = w23;
    red16[ch][base + 3 * 8 + 0] = w30; red16[ch][base + 3 * 8 + 1] = w31;
    red16[ch][base + 3 * 8 + 2] = w32; red16[ch][base + 3 * 8 + 3] = w33;
  }
  __syncthreads();

  if (t < 64) {
    float ws = 0.0f;
    #pragma unroll
    for (int c = 0; c < 16; ++c) ws += red16[c][t];
    const float sym = __shfl(ws, ((t & 7) << 3) | (t >> 3));  // W^T partner
    const float v = ws + sym;
    xbuf[bid * 64 + t] = v;
    float vmin = v, vmax = v;
    #pragma unroll
    for (int off = 32; off; off >>= 1) {
      vmin = fminf(vmin, __shfl_down(vmin, off));
      vmax = fmaxf(vmax, __shfl_down(vmax, off));
    }
    if (t == 0) { bmin[bid] = vmin; bmax[bid] = vmax; }
  }

  cgrp::this_grid().sync();

  // ======== PHASE B: table (blocks < NT; threads < 128 do the work) ========
  if (bid < NT) {
    float* actA = smem;          // [128]
    float* actB = smem + 128;    // [128]
    float* redA = smem + 256;    // [2]
    float* redB = smem + 260;    // [2]
    const int wv = t >> 6;

    float mn = 1e30f, mx = -1e30f;
    if (t < 128) {
      #pragma unroll
      for (int i = 0; i < 8; ++i) {
        mn = fminf(mn, bmin[t + i * 128]);
        mx = fmaxf(mx, bmax[t + i * 128]);
      }
    }
    #pragma unroll
    for (int off = 32; off; off >>= 1) {
      mn = fminf(mn, __shfl_xor(mn, off));
      mx = fmaxf(mx, __shfl_xor(mx, off));
    }
    if (t < 128 && (t & 63) == 0) { redA[wv] = mn; redB[wv] = mx; }
    __syncthreads();
    const float xmin = fminf(redA[0], redA[1]);
    const float xmax = fmaxf(redB[0], redB[1]);
    if (bid == 0 && t == 0) { mmf[0] = xmin; mmf[1] = xmax; }
    __syncthreads();

    const float x = xmin + (xmax - xmin) * ((float)bid / (float)(NT - 1));

    float lg = 0.0f;
    if (t < 128) lg = ew[t] * x + eb[t];
    float m = (t < 128) ? lg : -1e30f;
    #pragma unroll
    for (int off = 32; off; off >>= 1) m = fmaxf(m, __shfl_xor(m, off));
    if (t < 128 && (t & 63) == 0) redA[wv] = m;
    __syncthreads();
    m = fmaxf(redA[0], redA[1]);
    float ev = (t < 128) ? __expf(lg - m) : 0.0f;
    float s = ev;
    #pragma unroll
    for (int off = 32; off; off >>= 1) s += __shfl_xor(s, off);
    if (t < 128 && (t & 63) == 0) redB[wv] = s;
    __syncthreads();
    s = redB[0] + redB[1];
    if (t < 128) actA[t] = ev / s;
    __syncthreads();

    float h = 0.0f;
    if (t < 128) {
      const float4* w4 = (const float4*)(W1 + (size_t)t * 128);
      const float4* a4 = (const float4*)actA;
      float acc = 0.0f;
      #pragma unroll
      for (int kq = 0; kq < 32; ++kq) {
        float4 w = w4[kq]; float4 a = a4[kq];
        acc += w.x * a.x + w.y * a.y + w.z * a.z + w.w * a.w;
      }
      h = fmaxf(b1[t] + acc, 0.0f);
      actB[t] = h;
    }
    __syncthreads();
    if (t < 128) {
      const float4* w4 = (const float4*)(W2 + (size_t)t * 128);
      const float4* a4 = (const float4*)actB;
      float acc = 0.0f;
      #pragma unroll
      for (int kq = 0; kq < 32; ++kq) {
        float4 w = w4[kq]; float4 a = a4[kq];
        acc += w.x * a.x + w.y * a.y + w.z * a.z + w.w * a.w;
      }
      h = fmaxf(b2[t] + acc, 0.0f);
      actA[t] = h;
    }
    __syncthreads();
    float h3 = -1e30f;
    if (t < 128) {
      const float4* w4 = (const float4*)(W3 + (size_t)t * 128);
      const float4* a4 = (const float4*)actA;
      float acc = 0.0f;
      #pragma unroll
      for (int kq = 0; kq < 32; ++kq) {
        float4 w = w4[kq]; float4 a = a4[kq];
        acc += w.x * a.x + w.y * a.y + w.z * a.z + w.w * a.w;
      }
      h3 = b3[t] + acc;
    }
    float m3 = h3;
    #pragma unroll
    for (int off = 32; off; off >>= 1) m3 = fmaxf(m3, __shfl_xor(m3, off));
    __syncthreads();
    if (t < 128 && (t & 63) == 0) redA[wv] = m3;
    __syncthreads();
    m3 = fmaxf(redA[0], redA[1]);
    float e3 = (t < 128) ? __expf(h3 - m3) : 0.0f;
    float dn = e3;
    float nm = (t < 128) ? e3 * mup[t] : 0.0f;
    #pragma unroll
    for (int off = 32; off; off >>= 1) {
      dn += __shfl_xor(dn, off);
      nm += __shfl_xor(nm, off);
    }
    __syncthreads();
    if (t < 128 && (t & 63) == 0) { redA[wv] = dn; redB[wv] = nm; }
    __syncthreads();
    if (t == 0)
      table[bid] = lrp[0] * ((redB[0] + redB[1]) / (redA[0] + redA[1]));
  }

  cgrp::this_grid().sync();

  // ======== PHASE C: interp (blocks < 256 cover all 65536 outputs) ========
  if (bid < 256) {
    const int idx = bid * 256 + t;
    const float xmin = mmf[0];
    const float xmax = mmf[1];
    const float range = xmax - xmin;
    const float scale = (range > 0.0f) ? (float)(NT - 1) / range : 0.0f;
    float p = (xbuf[idx] - xmin) * scale;
    int i0 = (int)floorf(p);
    i0 = min(max(i0, 0), NT - 2);
    const float w = p - (float)i0;
    out[idx] = table[i0] + w * (table[i0 + 1] - table[i0]);
  }
}

extern "C" void kernel_launch(void* const* d_in, const int* in_sizes, int n_in,
                              void* d_out, int out_size, void* d_ws, size_t ws_size,
                              hipStream_t stream) {
  const float* pos  = (const float*)d_in[0];
  const float* cgr  = (const float*)d_in[1];
  const float* sigp = (const float*)d_in[2];
  const float* ew   = (const float*)d_in[3];
  const float* eb   = (const float*)d_in[4];
  const float* mup  = (const float*)d_in[5];
  const float* lrp  = (const float*)d_in[6];
  const float* W1   = (const float*)d_in[7];
  const float* b1   = (const float*)d_in[8];
  const float* W2   = (const float*)d_in[9];
  const float* b2   = (const float*)d_in[10];
  const float* W3   = (const float*)d_in[11];
  const float* b3   = (const float*)d_in[12];
  float* out = (float*)d_out;

  // ws layout (floats): [0..15] header (mmf at 0,1), xbuf[65536], table[NT],
  // bmin[1024], bmax[1024], ctg[972 floats = 1944 halves], consts[12]
  float* mmf    = (float*)d_ws;
  float* xbuf   = (float*)d_ws + 16;
  float* table  = xbuf + NOUT;
  float* bmin   = table + NT;
  float* bmax   = bmin + NBATCH;
  __half* ctg   = (__half*)(bmax + NBATCH);
  float* consts = (float*)(bmax + NBATCH) + 972;

  k_prep<<<1, 256, 0, stream>>>(cgr, sigp, ctg, consts);

  void* args[] = {
    (void*)&pos, (void*)&ctg, (void*)&consts,
    (void*)&ew, (void*)&eb, (void*)&mup, (void*)&lrp,
    (void*)&W1, (void*)&b1, (void*)&W2, (void*)&b2, (void*)&W3, (void*)&b3,
    (void*)&xbuf, (void*)&bmin, (void*)&bmax, (void*)&mmf,
    (void*)&table, (void*)&out
  };
  hipLaunchCooperativeKernel((void*)k_fused, dim3(NBATCH), dim3(256),
                             args, 0, stream);
}

// Round 16
// 39.394 us; speedup vs baseline: 5.4209x; 5.4209x over previous
//
#include <hip/hip_runtime.h>
#include <hip/hip_fp16.h>

#define NT 256          // f(x) table size
#define NBATCH 1024
#define NOUT 65536      // 1024*64

#if __has_builtin(__builtin_amdgcn_exp2f)
#define EXP2(x) __builtin_amdgcn_exp2f(x)
#else
#define EXP2(x) exp2f(x)
#endif

// ---- graph constants (baked from the reference) ----
__constant__ int c_e1[17] = {0,0,1,2,2,3,4,5,6,8,8,9,10,11,11,13,14};
__constant__ int c_e2[17] = {1,4,2,3,5,4,12,6,7,9,12,10,11,12,13,14,15};
__constant__ int c_p0[24] = {1,0,1,1,3,2,0,0,3,2,5,5,9,8,9,10,10,12,4,4,8,11,13,13};
__constant__ int c_p1[24] = {4,2,3,5,5,4,3,12,12,6,7,6,12,10,11,11,13,13,8,11,11,14,15,14};
__constant__ int c_ni[24] = {0,1,2,2,2,3,4,4,4,5,6,7,8,9,10,11,11,11,12,12,12,13,14,15};

// 6 unordered products (a<=b). E_ab symmetric => ovl = W + W^T,
// W = sum pref_ab * C_a E_ab C_b^T  (diagonal gets pref/2, folded into exp arg).
__constant__ int c_pa[6]   = {0,0,0,1,1,2};
__constant__ int c_pb[6]   = {0,1,2,1,2,2};
__constant__ int c_diag[6] = {1,0,0,1,0,1};

static __device__ __forceinline__ float2 up2(unsigned u) {
  __half2 h = *reinterpret_cast<__half2*>(&u);
  return __half22float2(h);
}

// ---- kernel 0: one-block prep — transformed fp16 C' + sigma consts ----
// Batch-invariant work hoisted out of the 1024-block hot kernel (per-block
// div/mod chains + stride-243 cg reads + fp16 cvt replaced by one coalesced
// uint4 copy). ctg is 3.9KB -> L2-resident for all 1024 blocks.
__global__ void k_prep(const float* __restrict__ cgr,
                       const float* __restrict__ sigp,
                       __half* __restrict__ ctg, float* __restrict__ consts) {
  const int t = threadIdx.x;
  for (int idx = t; idx < 3 * 81 * 8; idx += 256) {
    int s = idx / 648;
    int rem = idx - s * 648;
    int j = rem >> 3, q = rem & 7;
    int col = s * 81 + j;
    int off = j - 33;
    float v;
    if (off >= 0 && (off & 1)) v = -cgr[q * 243 + (col - 1)];
    else                       v =  cgr[q * 243 + col];
    ctg[idx] = __float2half(v);
  }
  if (t == 0) {
    float sg[3];
    sg[0] = 0.4f * __expf(sigp[0]);
    sg[1] = 0.8f * __expf(sigp[1]);
    sg[2] = 1.2f * __expf(sigp[2]);
    #pragma unroll
    for (int p = 0; p < 6; ++p) {
      float sa = sg[c_pa[p]], sb = sg[c_pb[p]];
      float s2 = sa * sa + sb * sb;
      float rr = 2.0f * sa * sb / s2;
      consts[p]     = (-0.5f / s2) * 1.44269504088896f;      // cInv (log2e folded)
      consts[6 + p] = 1.5f * __log2f(rr) - (float)c_diag[p]; // cLgp (diag: /2)
    }
  }
}

// ---- kernel 1: per-batch W; ovl = W + W^T ----
// PROVEN REGIME (r2/r3/r8/r9/r11/r12/r14 — best 37.5us): grid 1024, 256 thr,
// two-phase V->stage2 via LDS, no LDS atomics, NAMED scalar accumulators.
// Anti-patterns (each regressed 3-10x): accumulator arrays (r4-r7 scratch),
// per-lane uniform global loads in hot loop (r10), j-split across blocks
// (r13), mega-fusion/coop (r15: VGPR=28 spill, 213us).
// v16 = r14 + prep hoist: CT transform replaced by coalesced uint4 copy.
__global__ __launch_bounds__(256, 6)
void k_ovl(const float* __restrict__ pos, const __half* __restrict__ ctg,
           const float* __restrict__ consts, float* __restrict__ xout,
           float* __restrict__ bmin, float* __restrict__ bmax) {
  // smem floats: posS[48] | P4[81][4]=324 | CTh 1944 halves = 972 |
  // alias{ Vh 3888 halves = 1944 , red16[16][65] = 1040 } | cInv[6] cLgp[6]
  __shared__ __align__(16) float smem[3300];
  float* posS          = smem;                               // [48]
  float (*P4)[4]       = (float(*)[4])(smem + 48);           // [81][4]
  __half (*CTh)[81][8] = (__half(*)[81][8])(smem + 372);     // fp16 C'
  __half (*Vh)[81][8]  = (__half(*)[81][8])(smem + 1344);    // fp16 V
  float (*red16)[65]   = (float(*)[65])(smem + 1344);        // ALIAS of Vh
  float* cInv          = smem + 3288;                        // [6]
  float* cLgp          = smem + 3294;                        // [6]

  const int b = blockIdx.x;
  const int t = threadIdx.x;

  if (t < 48) posS[t] = pos[b * 48 + t];
  if (t < 243) ((uint4*)CTh)[t] = ((const uint4*)ctg)[t];    // coalesced copy
  if (t < 12) (smem + 3288)[t] = consts[t];                  // cInv|cLgp
  __syncthreads();

  // 81 block points: 16 atoms, 17 bond midpoints, 24 pairs x 2 cross points
  if (t < 81) {
    float x, y, z;
    if (t < 16) {
      x = posS[t * 3]; y = posS[t * 3 + 1]; z = posS[t * 3 + 2];
    } else if (t < 33) {
      int e = t - 16;
      int a0 = c_e1[e] * 3, a1 = c_e2[e] * 3;
      x = 0.5f * (posS[a0] + posS[a1]);
      y = 0.5f * (posS[a0 + 1] + posS[a1 + 1]);
      z = 0.5f * (posS[a0 + 2] + posS[a1 + 2]);
    } else {
      int k = (t - 33) >> 1, sgn = (t - 33) & 1;
      float sc = sgn ? 0.25f : -0.25f;
      int n = c_ni[k] * 3, a0 = c_p0[k] * 3, a1 = c_p1[k] * 3;
      x = posS[n]     + sc * (posS[a0]     - posS[a1]);
      y = posS[n + 1] + sc * (posS[a0 + 1] - posS[a1 + 1]);
      z = posS[n + 2] + sc * (posS[a0 + 2] - posS[a1 + 2]);
    }
    P4[t][0] = x; P4[t][1] = y; P4[t][2] = z;
    P4[t][3] = x * x + y * y + z * z;
  }
  __syncthreads();

  // ---- V phase: 246 tasks = (product s, 2-row strip); strip 40 = 1 row ----
  if (t < 246) {
    const int s = t / 41;
    const int st = t - s * 41;
    const int i0 = st * 2;
    const bool two = (st < 40);
    const int i1 = two ? i0 + 1 : i0;
    const int bb = c_pb[s];
    const float nInv = cInv[s];
    const float lgp  = cLgp[s];
    const float m2 = -2.0f * nInv;

    const float4 pA = *(const float4*)P4[i0];
    const float4 pB = *(const float4*)P4[i1];
    // folded: arg = qA.pj + (sj + cA),  qA = m2*pA, sj = nInv*pj.w
    const float qAx = m2 * pA.x, qAy = m2 * pA.y, qAz = m2 * pA.z;
    const float qBx = m2 * pB.x, qBy = m2 * pB.y, qBz = m2 * pB.z;
    const float cA = fmaf(pA.w, nInv, lgp);
    const float cB = fmaf(pB.w, nInv, lgp);

    // 8 NAMED half2 accumulators (packed fp16 FMA, 2/slot)
    __half2 a0 = __float2half2_rn(0.0f), a1 = a0, a2 = a0, a3 = a0;
    __half2 b0 = a0, b1 = a0, b2 = a0, b3 = a0;

    // singles: atoms + bond midpoints (j = 0..32)
    for (int j = 0; j < 33; ++j) {
      const float4 pj = *(const float4*)P4[j];
      const float sj = pj.w * nInv;
      const float aA = fmaf(qAx, pj.x, fmaf(qAy, pj.y, fmaf(qAz, pj.z, sj + cA)));
      const float aB = fmaf(qBx, pj.x, fmaf(qBy, pj.y, fmaf(qBz, pj.z, sj + cB)));
      const __half2 hA = __float2half2_rn(EXP2(aA));
      const __half2 hB = __float2half2_rn(EXP2(aB));
      const uint4 cu = *(const uint4*)&CTh[bb][j][0];   // 8 halves, one b128
      const __half2 c0 = *reinterpret_cast<const __half2*>(&cu.x);
      const __half2 c1 = *reinterpret_cast<const __half2*>(&cu.y);
      const __half2 c2 = *reinterpret_cast<const __half2*>(&cu.z);
      const __half2 c3 = *reinterpret_cast<const __half2*>(&cu.w);
      a0 = __hfma2(hA, c0, a0); a1 = __hfma2(hA, c1, a1);
      a2 = __hfma2(hA, c2, a2); a3 = __hfma2(hA, c3, a3);
      b0 = __hfma2(hB, c0, b0); b1 = __hfma2(hB, c1, b1);
      b2 = __hfma2(hB, c2, b2); b3 = __hfma2(hB, c3, b3);
    }

    // cross pairs: j+ = 33+2k (ct), j- = j+1 (-ct): (e+ - e-)*ct
    for (int k = 0; k < 24; ++k) {
      const int jp = 33 + (k << 1);
      const float4 pp = *(const float4*)P4[jp];
      const float4 pm = *(const float4*)P4[jp + 1];
      const float sp = pp.w * nInv;
      const float sm = pm.w * nInv;
      const float aAp = fmaf(qAx, pp.x, fmaf(qAy, pp.y, fmaf(qAz, pp.z, sp + cA)));
      const float aBp = fmaf(qBx, pp.x, fmaf(qBy, pp.y, fmaf(qBz, pp.z, sp + cB)));
      const float aAm = fmaf(qAx, pm.x, fmaf(qAy, pm.y, fmaf(qAz, pm.z, sm + cA)));
      const float aBm = fmaf(qBx, pm.x, fmaf(qBy, pm.y, fmaf(qBz, pm.z, sm + cB)));
      const __half2 hA = __float2half2_rn(EXP2(aAp) - EXP2(aAm));
      const __half2 hB = __float2half2_rn(EXP2(aBp) - EXP2(aBm));
      const uint4 cu = *(const uint4*)&CTh[bb][jp][0];
      const __half2 c0 = *reinterpret_cast<const __half2*>(&cu.x);
      const __half2 c1 = *reinterpret_cast<const __half2*>(&cu.y);
      const __half2 c2 = *reinterpret_cast<const __half2*>(&cu.z);
      const __half2 c3 = *reinterpret_cast<const __half2*>(&cu.w);
      a0 = __hfma2(hA, c0, a0); a1 = __hfma2(hA, c1, a1);
      a2 = __hfma2(hA, c2, a2); a3 = __hfma2(hA, c3, a3);
      b0 = __hfma2(hB, c0, b0); b1 = __hfma2(hB, c1, b1);
      b2 = __hfma2(hB, c2, b2); b3 = __hfma2(hB, c3, b3);
    }

    __half2* voA = (__half2*)&Vh[s][i0][0];
    voA[0] = a0; voA[1] = a1; voA[2] = a2; voA[3] = a3;
    if (two) {
      __half2* voB = (__half2*)&Vh[s][i0 + 1][0];
      voB[0] = b0; voB[1] = b1; voB[2] = b2; voB[3] = b3;
    }
  }
  __syncthreads();

  // ---- stage 2 (register-blocked 4x4, fp32 accum): W = sum CT^T * V ----
  float w00=0,w01=0,w02=0,w03=0, w10=0,w11=0,w12=0,w13=0;
  float w20=0,w21=0,w22=0,w23=0, w30=0,w31=0,w32=0,w33=0;
  const int ch = t & 15;
  if (t < 64) {
    const int pg = (t >> 5) & 1;
    const int qg = (t >> 4) & 1;
    const int ib = ch * 5;
    const int ie = (ch == 15) ? 81 : ib + 5;
    #pragma unroll
    for (int s = 0; s < 6; ++s) {
      const int lf = c_pa[s];
      for (int i = ib; i < ie; ++i) {
        const uint2 cu = *(const uint2*)&CTh[lf][i][pg * 4];
        const float2 p01 = up2(cu.x), p23 = up2(cu.y);
        const uint2 vu = *(const uint2*)&Vh[s][i][qg * 4];
        const float2 q01 = up2(vu.x), q23 = up2(vu.y);
        w00 = fmaf(p01.x, q01.x, w00); w01 = fmaf(p01.x, q01.y, w01);
        w02 = fmaf(p01.x, q23.x, w02); w03 = fmaf(p01.x, q23.y, w03);
        w10 = fmaf(p01.y, q01.x, w10); w11 = fmaf(p01.y, q01.y, w11);
        w12 = fmaf(p01.y, q23.x, w12); w13 = fmaf(p01.y, q23.y, w13);
        w20 = fmaf(p23.x, q01.x, w20); w21 = fmaf(p23.x, q01.y, w21);
        w22 = fmaf(p23.x, q23.x, w22); w23 = fmaf(p23.x, q23.y, w23);
        w30 = fmaf(p23.y, q01.x, w30); w31 = fmaf(p23.y, q01.y, w31);
        w32 = fmaf(p23.y, q23.x, w32); w33 = fmaf(p23.y, q23.y, w33);
      }
    }
  }
  __syncthreads();   // all Vh/CTh stage-2 reads done; red16 (alias) writable
  if (t < 64) {
    const int pg = (t >> 5) & 1;
    const int qg = (t >> 4) & 1;
    const int base = pg * 32 + qg * 4;
    red16[ch][base + 0 * 8 + 0] = w00; red16[ch][base + 0 * 8 + 1] = w01;
    red16[ch][base + 0 * 8 + 2] = w02; red16[ch][base + 0 * 8 + 3] = w03;
    red16[ch][base + 1 * 8 + 0] = w10; red16[ch][base + 1 * 8 + 1] = w11;
    red16[ch][base + 1 * 8 + 2] = w12; red16[ch][base + 1 * 8 + 3] = w13;
    red16[ch][base + 2 * 8 + 0] = w20; red16[ch][base + 2 * 8 + 1] = w21;
    red16[ch][base + 2 * 8 + 2] = w22; red16[ch][base + 2 * 8 + 3] = w23;
    red16[ch][base + 3 * 8 + 0] = w30; red16[ch][base + 3 * 8 + 1] = w31;
    red16[ch][base + 3 * 8 + 2] = w32; red16[ch][base + 3 * 8 + 3] = w33;
  }
  __syncthreads();

  if (t < 64) {
    float ws = 0.0f;
    #pragma unroll
    for (int c = 0; c < 16; ++c) ws += red16[c][t];
    const float sym = __shfl(ws, ((t & 7) << 3) | (t >> 3));  // W^T partner
    const float v = ws + sym;
    xout[b * 64 + t] = v;
    float vmin = v, vmax = v;
    #pragma unroll
    for (int off = 32; off; off >>= 1) {
      vmin = fminf(vmin, __shfl_down(vmin, off));
      vmax = fmaxf(vmax, __shfl_down(vmax, off));
    }
    if (t == 0) { bmin[b] = vmin; bmax[b] = vmax; }
  }
}

// ---- kernel 2: tabulate f(x) at NT nodes; full fp32 MLP per node ----
__device__ __forceinline__ float dot128(const float* __restrict__ W,
                                        const float* __restrict__ act, int t) {
  const float4* w4 = (const float4*)(W + (size_t)t * 128);
  const float4* a4 = (const float4*)act;
  float acc = 0.0f;
  #pragma unroll
  for (int kq = 0; kq < 32; ++kq) {
    float4 w = w4[kq];
    float4 a = a4[kq];
    acc += w.x * a.x + w.y * a.y + w.z * a.z + w.w * a.w;
  }
  return acc;
}

__global__ __launch_bounds__(128)
void k_table(const float* __restrict__ ew, const float* __restrict__ eb,
             const float* __restrict__ mup, const float* __restrict__ lrp,
             const float* __restrict__ W1, const float* __restrict__ b1,
             const float* __restrict__ W2, const float* __restrict__ b2,
             const float* __restrict__ W3, const float* __restrict__ b3,
             const float* __restrict__ bmin, const float* __restrict__ bmax,
             float* __restrict__ mmf, float* __restrict__ table) {
  __shared__ __align__(16) float actA[128];
  __shared__ __align__(16) float actB[128];
  __shared__ float red[2];
  __shared__ float red2[2];
  const int t = threadIdx.x;
  const int wv = t >> 6;

  // reduce the per-block min/max arrays (1024 each, L2-resident)
  float mn = 1e30f, mx = -1e30f;
  #pragma unroll
  for (int i = 0; i < 8; ++i) {
    mn = fminf(mn, bmin[t + i * 128]);
    mx = fmaxf(mx, bmax[t + i * 128]);
  }
  #pragma unroll
  for (int off = 32; off; off >>= 1) {
    mn = fminf(mn, __shfl_xor(mn, off));
    mx = fmaxf(mx, __shfl_xor(mx, off));
  }
  if ((t & 63) == 0) { red[wv] = mn; red2[wv] = mx; }
  __syncthreads();
  const float xmin = fminf(red[0], red[1]);
  const float xmax = fmaxf(red2[0], red2[1]);
  if (blockIdx.x == 0 && t == 0) { mmf[0] = xmin; mmf[1] = xmax; }
  __syncthreads();

  const float x = xmin + (xmax - xmin) * ((float)blockIdx.x / (float)(NT - 1));

  // encoder softmax: e = softmax(ew*x + eb)
  float lg = ew[t] * x + eb[t];
  float m = lg;
  #pragma unroll
  for (int off = 32; off; off >>= 1) m = fmaxf(m, __shfl_xor(m, off));
  if ((t & 63) == 0) red[wv] = m;
  __syncthreads();
  m = fmaxf(red[0], red[1]);
  float ev = __expf(lg - m);
  float s = ev;
  #pragma unroll
  for (int off = 32; off; off >>= 1) s += __shfl_xor(s, off);
  if ((t & 63) == 0) red2[wv] = s;
  __syncthreads();
  s = red2[0] + red2[1];
  actA[t] = ev / s;
  __syncthreads();

  float h = fmaxf(b1[t] + dot128(W1, actA, t), 0.0f);
  actB[t] = h;
  __syncthreads();
  h = fmaxf(b2[t] + dot128(W2, actB, t), 0.0f);
  actA[t] = h;
  __syncthreads();
  float h3 = b3[t] + dot128(W3, actA, t);

  float m3 = h3;
  #pragma unroll
  for (int off = 32; off; off >>= 1) m3 = fmaxf(m3, __shfl_xor(m3, off));
  __syncthreads();
  if ((t & 63) == 0) red[wv] = m3;
  __syncthreads();
  m3 = fmaxf(red[0], red[1]);
  float e3 = __expf(h3 - m3);
  float dn = e3;
  float nm = e3 * mup[t];
  #pragma unroll
  for (int off = 32; off; off >>= 1) {
    dn += __shfl_xor(dn, off);
    nm += __shfl_xor(nm, off);
  }
  __syncthreads();
  if ((t & 63) == 0) { red[wv] = dn; red2[wv] = nm; }
  __syncthreads();
  if (t == 0)
    table[blockIdx.x] = lrp[0] * ((red2[0] + red2[1]) / (red[0] + red[1]));
}

// ---- kernel 3: linear interpolation of the table at each x ----
__global__ __launch_bounds__(256)
void k_interp(const float* __restrict__ xbuf, const float* __restrict__ table,
              const float* __restrict__ mmf, float* __restrict__ out, int n) {
  const int r = blockIdx.x * 256 + threadIdx.x;
  if (r >= n) return;
  const float xmin = mmf[0];
  const float xmax = mmf[1];
  const float range = xmax - xmin;
  const float scale = (range > 0.0f) ? (float)(NT - 1) / range : 0.0f;
  float p = (xbuf[r] - xmin) * scale;
  int i0 = (int)floorf(p);
  i0 = min(max(i0, 0), NT - 2);
  const float w = p - (float)i0;
  out[r] = table[i0] + w * (table[i0 + 1] - table[i0]);
}

extern "C" void kernel_launch(void* const* d_in, const int* in_sizes, int n_in,
                              void* d_out, int out_size, void* d_ws, size_t ws_size,
                              hipStream_t stream) {
  const float* pos  = (const float*)d_in[0];
  const float* cgr  = (const float*)d_in[1];
  const float* sigp = (const float*)d_in[2];
  const float* ew   = (const float*)d_in[3];
  const float* eb   = (const float*)d_in[4];
  const float* mup  = (const float*)d_in[5];
  const float* lrp  = (const float*)d_in[6];
  const float* W1   = (const float*)d_in[7];
  const float* b1   = (const float*)d_in[8];
  const float* W2   = (const float*)d_in[9];
  const float* b2   = (const float*)d_in[10];
  const float* W3   = (const float*)d_in[11];
  const float* b3   = (const float*)d_in[12];
  float* out = (float*)d_out;

  // ws layout (floats): [0..15] header (mmf at 0,1), xbuf[65536], table[NT],
  // bmin[1024], bmax[1024], ctg[972 floats = 1944 halves], consts[12]
  float* mmf    = (float*)d_ws;
  float* xbuf   = (float*)d_ws + 16;
  float* table  = xbuf + NOUT;
  float* bmin   = table + NT;
  float* bmax   = bmin + NBATCH;
  __half* ctg   = (__half*)(bmax + NBATCH);
  float* consts = (float*)(bmax + NBATCH) + 972;

  k_prep<<<1, 256, 0, stream>>>(cgr, sigp, ctg, consts);
  k_ovl<<<NBATCH, 256, 0, stream>>>(pos, ctg, consts, xbuf, bmin, bmax);
  k_table<<<NT, 128, 0, stream>>>(ew, eb, mup, lrp, W1, b1, W2, b2, W3, b3,
                                  bmin, bmax, mmf, table);
  k_interp<<<(NOUT + 255) / 256, 256, 0, stream>>>(xbuf, table, mmf, out, NOUT);
}

// Round 17
// 37.195 us; speedup vs baseline: 5.7413x; 1.0591x over previous
//
#include <hip/hip_runtime.h>
#include <hip/hip_fp16.h>

#define NT 256          // f(x) table size
#define NBATCH 1024
#define NOUT 65536      // 1024*64

#if __has_builtin(__builtin_amdgcn_exp2f)
#define EXP2(x) __builtin_amdgcn_exp2f(x)
#else
#define EXP2(x) exp2f(x)
#endif

// ---- graph constants (baked from the reference) ----
__constant__ int c_e1[17] = {0,0,1,2,2,3,4,5,6,8,8,9,10,11,11,13,14};
__constant__ int c_e2[17] = {1,4,2,3,5,4,12,6,7,9,12,10,11,12,13,14,15};
__constant__ int c_p0[24] = {1,0,1,1,3,2,0,0,3,2,5,5,9,8,9,10,10,12,4,4,8,11,13,13};
__constant__ int c_p1[24] = {4,2,3,5,5,4,3,12,12,6,7,6,12,10,11,11,13,13,8,11,11,14,15,14};
__constant__ int c_ni[24] = {0,1,2,2,2,3,4,4,4,5,6,7,8,9,10,11,11,11,12,12,12,13,14,15};

// 6 unordered products (a<=b). E_ab symmetric => ovl = W + W^T,
// W = sum pref_ab * C_a E_ab C_b^T  (diagonal gets pref/2, folded into exp arg).
__constant__ int c_pa[6]   = {0,0,0,1,1,2};
__constant__ int c_pb[6]   = {0,1,2,1,2,2};
__constant__ int c_diag[6] = {1,0,0,1,0,1};

static __device__ __forceinline__ float2 up2(unsigned u) {
  __half2 h = *reinterpret_cast<__half2*>(&u);
  return __half22float2(h);
}

// ---- kernel 1: per-batch W; ovl = W + W^T ----
// FINAL CONFIG = r14 (measured best, 37.5us). PROVEN REGIME: grid 1024,
// 256 thr, two-phase V->stage2 via LDS, no LDS atomics, NAMED scalar
// accumulators, fp16-packed CT/V (__hfma2), exp-arg folding, E-symmetry
// (6 products, ovl=W+W^T), 2-row strips (246/256 threads active).
// Anti-patterns (each regressed 1.1-10x): accumulator arrays (r4-r7:
// scratch demotion), per-lane uniform global loads in hot loop (r10:
// 571MB HBM), j-split across blocks (r13: duplicated fixed work),
// coop mega-fusion (r15: VGPR=28 spill), prep-hoist extra dispatch (r16).
__global__ __launch_bounds__(256, 6)
void k_ovl(const float* __restrict__ pos, const float* __restrict__ cg,
           const float* __restrict__ sigp, float* __restrict__ xout,
           float* __restrict__ bmin, float* __restrict__ bmax) {
  // smem floats: posS[48] | P4[81][4]=324 | CTh 1944 halves = 972 |
  // alias{ Vh 3888 halves = 1944 , red16[16][65] = 1040 } | cInv[6] cLgp[6]
  __shared__ __align__(16) float smem[3300];
  float* posS          = smem;                               // [48]
  float (*P4)[4]       = (float(*)[4])(smem + 48);           // [81][4]
  __half (*CTh)[81][8] = (__half(*)[81][8])(smem + 372);     // fp16 C'
  __half (*Vh)[81][8]  = (__half(*)[81][8])(smem + 1344);    // fp16 V
  float (*red16)[65]   = (float(*)[65])(smem + 1344);        // ALIAS of Vh
  float* cInv          = smem + 3288;                        // [6]
  float* cLgp          = smem + 3294;                        // [6]

  const int b = blockIdx.x;
  const int t = threadIdx.x;

  if (t < 48) posS[t] = pos[b * 48 + t];

  // make_opposite_blocks: odd cross cols (j>=33, odd offset) = -C[:,col-1]
  for (int idx = t; idx < 3 * 81 * 8; idx += 256) {
    int s = idx / 648;
    int rem = idx - s * 648;
    int j = rem >> 3, q = rem & 7;
    int col = s * 81 + j;
    int off = j - 33;
    float v;
    if (off >= 0 && (off & 1)) v = -cg[q * 243 + (col - 1)];
    else                       v =  cg[q * 243 + col];
    ((__half*)CTh)[idx] = __float2half(v);
  }

  if (t == 0) {
    float sg[3];
    sg[0] = 0.4f * __expf(sigp[0]);
    sg[1] = 0.8f * __expf(sigp[1]);
    sg[2] = 1.2f * __expf(sigp[2]);
    #pragma unroll
    for (int p = 0; p < 6; ++p) {
      float sa = sg[c_pa[p]], sb = sg[c_pb[p]];
      float s2 = sa * sa + sb * sb;
      float rr = 2.0f * sa * sb / s2;
      cLgp[p] = 1.5f * __log2f(rr) - (float)c_diag[p];  // diag: pref/2
      cInv[p] = (-0.5f / s2) * 1.44269504088896f;       // includes log2(e)
    }
  }
  __syncthreads();

  // 81 block points: 16 atoms, 17 bond midpoints, 24 pairs x 2 cross points
  if (t < 81) {
    float x, y, z;
    if (t < 16) {
      x = posS[t * 3]; y = posS[t * 3 + 1]; z = posS[t * 3 + 2];
    } else if (t < 33) {
      int e = t - 16;
      int a0 = c_e1[e] * 3, a1 = c_e2[e] * 3;
      x = 0.5f * (posS[a0] + posS[a1]);
      y = 0.5f * (posS[a0 + 1] + posS[a1 + 1]);
      z = 0.5f * (posS[a0 + 2] + posS[a1 + 2]);
    } else {
      int k = (t - 33) >> 1, sgn = (t - 33) & 1;
      float sc = sgn ? 0.25f : -0.25f;
      int n = c_ni[k] * 3, a0 = c_p0[k] * 3, a1 = c_p1[k] * 3;
      x = posS[n]     + sc * (posS[a0]     - posS[a1]);
      y = posS[n + 1] + sc * (posS[a0 + 1] - posS[a1 + 1]);
      z = posS[n + 2] + sc * (posS[a0 + 2] - posS[a1 + 2]);
    }
    P4[t][0] = x; P4[t][1] = y; P4[t][2] = z;
    P4[t][3] = x * x + y * y + z * z;
  }
  __syncthreads();

  // ---- V phase: 246 tasks = (product s, 2-row strip); strip 40 = 1 row ----
  if (t < 246) {
    const int s = t / 41;
    const int st = t - s * 41;
    const int i0 = st * 2;
    const bool two = (st < 40);
    const int i1 = two ? i0 + 1 : i0;
    const int bb = c_pb[s];
    const float nInv = cInv[s];
    const float lgp  = cLgp[s];
    const float m2 = -2.0f * nInv;

    const float4 pA = *(const float4*)P4[i0];
    const float4 pB = *(const float4*)P4[i1];
    // folded: arg = qA.pj + (sj + cA),  qA = m2*pA, sj = nInv*pj.w
    const float qAx = m2 * pA.x, qAy = m2 * pA.y, qAz = m2 * pA.z;
    const float qBx = m2 * pB.x, qBy = m2 * pB.y, qBz = m2 * pB.z;
    const float cA = fmaf(pA.w, nInv, lgp);
    const float cB = fmaf(pB.w, nInv, lgp);

    // 8 NAMED half2 accumulators (packed fp16 FMA, 2/slot)
    __half2 a0 = __float2half2_rn(0.0f), a1 = a0, a2 = a0, a3 = a0;
    __half2 b0 = a0, b1 = a0, b2 = a0, b3 = a0;

    // singles: atoms + bond midpoints (j = 0..32)
    for (int j = 0; j < 33; ++j) {
      const float4 pj = *(const float4*)P4[j];
      const float sj = pj.w * nInv;
      const float aA = fmaf(qAx, pj.x, fmaf(qAy, pj.y, fmaf(qAz, pj.z, sj + cA)));
      const float aB = fmaf(qBx, pj.x, fmaf(qBy, pj.y, fmaf(qBz, pj.z, sj + cB)));
      const __half2 hA = __float2half2_rn(EXP2(aA));
      const __half2 hB = __float2half2_rn(EXP2(aB));
      const uint4 cu = *(const uint4*)&CTh[bb][j][0];   // 8 halves, one b128
      const __half2 c0 = *reinterpret_cast<const __half2*>(&cu.x);
      const __half2 c1 = *reinterpret_cast<const __half2*>(&cu.y);
      const __half2 c2 = *reinterpret_cast<const __half2*>(&cu.z);
      const __half2 c3 = *reinterpret_cast<const __half2*>(&cu.w);
      a0 = __hfma2(hA, c0, a0); a1 = __hfma2(hA, c1, a1);
      a2 = __hfma2(hA, c2, a2); a3 = __hfma2(hA, c3, a3);
      b0 = __hfma2(hB, c0, b0); b1 = __hfma2(hB, c1, b1);
      b2 = __hfma2(hB, c2, b2); b3 = __hfma2(hB, c3, b3);
    }

    // cross pairs: j+ = 33+2k (ct), j- = j+1 (-ct): (e+ - e-)*ct
    for (int k = 0; k < 24; ++k) {
      const int jp = 33 + (k << 1);
      const float4 pp = *(const float4*)P4[jp];
      const float4 pm = *(const float4*)P4[jp + 1];
      const float sp = pp.w * nInv;
      const float sm = pm.w * nInv;
      const float aAp = fmaf(qAx, pp.x, fmaf(qAy, pp.y, fmaf(qAz, pp.z, sp + cA)));
      const float aBp = fmaf(qBx, pp.x, fmaf(qBy, pp.y, fmaf(qBz, pp.z, sp + cB)));
      const float aAm = fmaf(qAx, pm.x, fmaf(qAy, pm.y, fmaf(qAz, pm.z, sm + cA)));
      const float aBm = fmaf(qBx, pm.x, fmaf(qBy, pm.y, fmaf(qBz, pm.z, sm + cB)));
      const __half2 hA = __float2half2_rn(EXP2(aAp) - EXP2(aAm));
      const __half2 hB = __float2half2_rn(EXP2(aBp) - EXP2(aBm));
      const uint4 cu = *(const uint4*)&CTh[bb][jp][0];
      const __half2 c0 = *reinterpret_cast<const __half2*>(&cu.x);
      const __half2 c1 = *reinterpret_cast<const __half2*>(&cu.y);
      const __half2 c2 = *reinterpret_cast<const __half2*>(&cu.z);
      const __half2 c3 = *reinterpret_cast<const __half2*>(&cu.w);
      a0 = __hfma2(hA, c0, a0); a1 = __hfma2(hA, c1, a1);
      a2 = __hfma2(hA, c2, a2); a3 = __hfma2(hA, c3, a3);
      b0 = __hfma2(hB, c0, b0); b1 = __hfma2(hB, c1, b1);
      b2 = __hfma2(hB, c2, b2); b3 = __hfma2(hB, c3, b3);
    }

    __half2* voA = (__half2*)&Vh[s][i0][0];
    voA[0] = a0; voA[1] = a1; voA[2] = a2; voA[3] = a3;
    if (two) {
      __half2* voB = (__half2*)&Vh[s][i0 + 1][0];
      voB[0] = b0; voB[1] = b1; voB[2] = b2; voB[3] = b3;
    }
  }
  __syncthreads();

  // ---- stage 2 (register-blocked 4x4, fp32 accum): W = sum CT^T * V ----
  float w00=0,w01=0,w02=0,w03=0, w10=0,w11=0,w12=0,w13=0;
  float w20=0,w21=0,w22=0,w23=0, w30=0,w31=0,w32=0,w33=0;
  const int ch = t & 15;
  if (t < 64) {
    const int pg = (t >> 5) & 1;
    const int qg = (t >> 4) & 1;
    const int ib = ch * 5;
    const int ie = (ch == 15) ? 81 : ib + 5;
    #pragma unroll
    for (int s = 0; s < 6; ++s) {
      const int lf = c_pa[s];
      for (int i = ib; i < ie; ++i) {
        const uint2 cu = *(const uint2*)&CTh[lf][i][pg * 4];
        const float2 p01 = up2(cu.x), p23 = up2(cu.y);
        const uint2 vu = *(const uint2*)&Vh[s][i][qg * 4];
        const float2 q01 = up2(vu.x), q23 = up2(vu.y);
        w00 = fmaf(p01.x, q01.x, w00); w01 = fmaf(p01.x, q01.y, w01);
        w02 = fmaf(p01.x, q23.x, w02); w03 = fmaf(p01.x, q23.y, w03);
        w10 = fmaf(p01.y, q01.x, w10); w11 = fmaf(p01.y, q01.y, w11);
        w12 = fmaf(p01.y, q23.x, w12); w13 = fmaf(p01.y, q23.y, w13);
        w20 = fmaf(p23.x, q01.x, w20); w21 = fmaf(p23.x, q01.y, w21);
        w22 = fmaf(p23.x, q23.x, w22); w23 = fmaf(p23.x, q23.y, w23);
        w30 = fmaf(p23.y, q01.x, w30); w31 = fmaf(p23.y, q01.y, w31);
        w32 = fmaf(p23.y, q23.x, w32); w33 = fmaf(p23.y, q23.y, w33);
      }
    }
  }
  __syncthreads();   // all Vh/CTh stage-2 reads done; red16 (alias) writable
  if (t < 64) {
    const int pg = (t >> 5) & 1;
    const int qg = (t >> 4) & 1;
    const int base = pg * 32 + qg * 4;
    red16[ch][base + 0 * 8 + 0] = w00; red16[ch][base + 0 * 8 + 1] = w01;
    red16[ch][base + 0 * 8 + 2] = w02; red16[ch][base + 0 * 8 + 3] = w03;
    red16[ch][base + 1 * 8 + 0] = w10; red16[ch][base + 1 * 8 + 1] = w11;
    red16[ch][base + 1 * 8 + 2] = w12; red16[ch][base + 1 * 8 + 3] = w13;
    red16[ch][base + 2 * 8 + 0] = w20; red16[ch][base + 2 * 8 + 1] = w21;
    red16[ch][base + 2 * 8 + 2] = w22; red16[ch][base + 2 * 8 + 3] = w23;
    red16[ch][base + 3 * 8 + 0] = w30; red16[ch][base + 3 * 8 + 1] = w31;
    red16[ch][base + 3 * 8 + 2] = w32; red16[ch][base + 3 * 8 + 3] = w33;
  }
  __syncthreads();

  if (t < 64) {
    float ws = 0.0f;
    #pragma unroll
    for (int c = 0; c < 16; ++c) ws += red16[c][t];
    const float sym = __shfl(ws, ((t & 7) << 3) | (t >> 3));  // W^T partner
    const float v = ws + sym;
    xout[b * 64 + t] = v;
    float vmin = v, vmax = v;
    #pragma unroll
    for (int off = 32; off; off >>= 1) {
      vmin = fminf(vmin, __shfl_down(vmin, off));
      vmax = fmaxf(vmax, __shfl_down(vmax, off));
    }
    if (t == 0) { bmin[b] = vmin; bmax[b] = vmax; }
  }
}

// ---- kernel 2: tabulate f(x) at NT nodes; full fp32 MLP per node ----
__device__ __forceinline__ float dot128(const float* __restrict__ W,
                                        const float* __restrict__ act, int t) {
  const float4* w4 = (const float4*)(W + (size_t)t * 128);
  const float4* a4 = (const float4*)act;
  float acc = 0.0f;
  #pragma unroll
  for (int kq = 0; kq < 32; ++kq) {
    float4 w = w4[kq];
    float4 a = a4[kq];
    acc += w.x * a.x + w.y * a.y + w.z * a.z + w.w * a.w;
  }
  return acc;
}

__global__ __launch_bounds__(128)
void k_table(const float* __restrict__ ew, const float* __restrict__ eb,
             const float* __restrict__ mup, const float* __restrict__ lrp,
             const float* __restrict__ W1, const float* __restrict__ b1,
             const float* __restrict__ W2, const float* __restrict__ b2,
             const float* __restrict__ W3, const float* __restrict__ b3,
             const float* __restrict__ bmin, const float* __restrict__ bmax,
             float* __restrict__ mmf, float* __restrict__ table) {
  __shared__ __align__(16) float actA[128];
  __shared__ __align__(16) float actB[128];
  __shared__ float red[2];
  __shared__ float red2[2];
  const int t = threadIdx.x;
  const int wv = t >> 6;

  // reduce the per-block min/max arrays (1024 each, L2-resident)
  float mn = 1e30f, mx = -1e30f;
  #pragma unroll
  for (int i = 0; i < 8; ++i) {
    mn = fminf(mn, bmin[t + i * 128]);
    mx = fmaxf(mx, bmax[t + i * 128]);
  }
  #pragma unroll
  for (int off = 32; off; off >>= 1) {
    mn = fminf(mn, __shfl_xor(mn, off));
    mx = fmaxf(mx, __shfl_xor(mx, off));
  }
  if ((t & 63) == 0) { red[wv] = mn; red2[wv] = mx; }
  __syncthreads();
  const float xmin = fminf(red[0], red[1]);
  const float xmax = fmaxf(red2[0], red2[1]);
  if (blockIdx.x == 0 && t == 0) { mmf[0] = xmin; mmf[1] = xmax; }
  __syncthreads();

  const float x = xmin + (xmax - xmin) * ((float)blockIdx.x / (float)(NT - 1));

  // encoder softmax: e = softmax(ew*x + eb)
  float lg = ew[t] * x + eb[t];
  float m = lg;
  #pragma unroll
  for (int off = 32; off; off >>= 1) m = fmaxf(m, __shfl_xor(m, off));
  if ((t & 63) == 0) red[wv] = m;
  __syncthreads();
  m = fmaxf(red[0], red[1]);
  float ev = __expf(lg - m);
  float s = ev;
  #pragma unroll
  for (int off = 32; off; off >>= 1) s += __shfl_xor(s, off);
  if ((t & 63) == 0) red2[wv] = s;
  __syncthreads();
  s = red2[0] + red2[1];
  actA[t] = ev / s;
  __syncthreads();

  float h = fmaxf(b1[t] + dot128(W1, actA, t), 0.0f);
  actB[t] = h;
  __syncthreads();
  h = fmaxf(b2[t] + dot128(W2, actB, t), 0.0f);
  actA[t] = h;
  __syncthreads();
  float h3 = b3[t] + dot128(W3, actA, t);

  float m3 = h3;
  #pragma unroll
  for (int off = 32; off; off >>= 1) m3 = fmaxf(m3, __shfl_xor(m3, off));
  __syncthreads();
  if ((t & 63) == 0) red[wv] = m3;
  __syncthreads();
  m3 = fmaxf(red[0], red[1]);
  float e3 = __expf(h3 - m3);
  float dn = e3;
  float nm = e3 * mup[t];
  #pragma unroll
  for (int off = 32; off; off >>= 1) {
    dn += __shfl_xor(dn, off);
    nm += __shfl_xor(nm, off);
  }
  __syncthreads();
  if ((t & 63) == 0) { red[wv] = dn; red2[wv] = nm; }
  __syncthreads();
  if (t == 0)
    table[blockIdx.x] = lrp[0] * ((red2[0] + red2[1]) / (red[0] + red[1]));
}

// ---- kernel 3: linear interpolation of the table at each x ----
__global__ __launch_bounds__(256)
void k_interp(const float* __restrict__ xbuf, const float* __restrict__ table,
              const float* __restrict__ mmf, float* __restrict__ out, int n) {
  const int r = blockIdx.x * 256 + threadIdx.x;
  if (r >= n) return;
  const float xmin = mmf[0];
  const float xmax = mmf[1];
  const float range = xmax - xmin;
  const float scale = (range > 0.0f) ? (float)(NT - 1) / range : 0.0f;
  float p = (xbuf[r] - xmin) * scale;
  int i0 = (int)floorf(p);
  i0 = min(max(i0, 0), NT - 2);
  const float w = p - (float)i0;
  out[r] = table[i0] + w * (table[i0 + 1] - table[i0]);
}

extern "C" void kernel_launch(void* const* d_in, const int* in_sizes, int n_in,
                              void* d_out, int out_size, void* d_ws, size_t ws_size,
                              hipStream_t stream) {
  const float* pos  = (const float*)d_in[0];
  const float* cg   = (const float*)d_in[1];
  const float* sigp = (const float*)d_in[2];
  const float* ew   = (const float*)d_in[3];
  const float* eb   = (const float*)d_in[4];
  const float* mup  = (const float*)d_in[5];
  const float* lrp  = (const float*)d_in[6];
  const float* W1   = (const float*)d_in[7];
  const float* b1   = (const float*)d_in[8];
  const float* W2   = (const float*)d_in[9];
  const float* b2   = (const float*)d_in[10];
  const float* W3   = (const float*)d_in[11];
  const float* b3   = (const float*)d_in[12];
  float* out = (float*)d_out;

  // ws layout (floats): [0..15] header (mmf at 0,1), xbuf[65536], table[NT],
  // bmin[1024], bmax[1024]
  float* mmf   = (float*)d_ws;
  float* xbuf  = (float*)d_ws + 16;
  float* table = xbuf + NOUT;
  float* bmin  = table + NT;
  float* bmax  = bmin + NBATCH;

  k_ovl<<<NBATCH, 256, 0, stream>>>(pos, cg, sigp, xbuf, bmin, bmax);
  k_table<<<NT, 128, 0, stream>>>(ew, eb, mup, lrp, W1, b1, W2, b2, W3, b3,
                                  bmin, bmax, mmf, table);
  k_interp<<<(NOUT + 255) / 256, 256, 0, stream>>>(xbuf, table, mmf, out, NOUT);
}